// Round 1
// baseline (554.818 us; speedup 1.0000x reference)
//
#include <hip/hip_runtime.h>

// Problem constants
#define BB 64
#define SS 2048
#define DD 512

typedef __attribute__((ext_vector_type(8))) short bf16x8;
typedef __attribute__((ext_vector_type(4))) float f32x4;

// fp32 -> bf16 bits, round-to-nearest-even
__device__ __forceinline__ unsigned f2bf(float f) {
    unsigned u = __float_as_uint(f);
    u += 0x7FFFu + ((u >> 16) & 1u);
    return u >> 16;
}

__device__ __forceinline__ float fast_tanh(float x) {
    float ax = fabsf(x);
    float e = __expf(-2.0f * ax);                       // (0,1], never overflows
    float t = (1.0f - e) * __builtin_amdgcn_rcpf(1.0f + e);
    return x < 0.0f ? -t : t;
}

// ---------------------------------------------------------------------------
// Prep 1: Bt[n][k] = bf16(W_t[512+k][n]).  64x64 LDS tile transpose.
__global__ void prep_w(const float* __restrict__ W, short* __restrict__ Bt) {
    __shared__ float tile[64][65];
    int kt = blockIdx.x >> 3;      // 8 x 8 tiles
    int nt = blockIdx.x & 7;
    int t = threadIdx.x;
    int c = t & 63;
    int rbase = (t >> 6) * 16;
    #pragma unroll
    for (int i = 0; i < 16; ++i) {
        int r = rbase + i;
        tile[r][c] = W[(size_t)(512 + kt * 64 + r) * DD + nt * 64 + c];
    }
    __syncthreads();
    #pragma unroll
    for (int i = 0; i < 16; ++i) {
        int r = rbase + i;
        Bt[(size_t)(nt * 64 + r) * DD + kt * 64 + c] = (short)f2bf(tile[c][r]);
    }
}

// Prep 2: p[b][d] = sum_e dec[b][e] * W_t[e][d] + b_t[d]   (fp32, exact)
__global__ void prep_p(const float* __restrict__ dec, const float* __restrict__ W,
                       const float* __restrict__ bt, float* __restrict__ p) {
    int b = blockIdx.x;
    int d = blockIdx.y * 256 + threadIdx.x;
    float acc = bt[d];
    const float* dv = dec + (size_t)b * DD;
    #pragma unroll 8
    for (int e = 0; e < DD; ++e)
        acc += dv[e] * W[(size_t)e * DD + d];
    p[(size_t)b * DD + d] = acc;
}

// ---------------------------------------------------------------------------
// hi/lo bf16 split write of a 4-float group into the two LDS tiles.
__device__ __forceinline__ void write_slab(char* AhiB, char* AloB, unsigned off, f32x4 x) {
    unsigned hb0 = f2bf(x.x), hb1 = f2bf(x.y), hb2 = f2bf(x.z), hb3 = f2bf(x.w);
    uint2 hv;
    hv.x = hb0 | (hb1 << 16);
    hv.y = hb2 | (hb3 << 16);
    float r0 = x.x - __uint_as_float(hb0 << 16);
    float r1 = x.y - __uint_as_float(hb1 << 16);
    float r2 = x.z - __uint_as_float(hb2 << 16);
    float r3 = x.w - __uint_as_float(hb3 << 16);
    uint2 lv;
    lv.x = f2bf(r0) | (f2bf(r1) << 16);
    lv.y = f2bf(r2) | (f2bf(r3) << 16);
    *(uint2*)(AhiB + off) = hv;
    *(uint2*)(AloB + off) = lv;
}

// ---------------------------------------------------------------------------
// Fused: score GEMM (full N=512 per block) + tanh·v epilogue + chunk-local
// softmax partials + partial context, all from ONE read of enc.
//
// Block = (batch b, 64-row s-chunk). 512 threads = 8 waves, wave w owns
// n-slice [w*64, w*64+64): acc = 4 m-frags x 4 n-frags (64 VGPR).
// enc tile staged to LDS as bf16 hi (GEMM operand) + bf16 lo (hi+lo ~= fp32
// for the exact context partial). 16 k-slabs, distance-2 register prefetch,
// one barrier per slab -> MFMA hides under the HBM stream. B-frags come
// straight from L2 (Bt = 512 KB, resident).
// LDS swizzle: within-row byte offset XOR ((row&7)<<4) on both write and
// read sides (row stride 1024 B would otherwise be a 16-way bank conflict).
__global__ __launch_bounds__(512, 2)
void fused_k(const float* __restrict__ enc, const short* __restrict__ Bt,
             const float* __restrict__ p, const float* __restrict__ va,
             float* __restrict__ score, float* __restrict__ ml,
             float* __restrict__ pctx) {
    __shared__ short Ahi[64 * 512];   // 64 KB
    __shared__ short Alo[64 * 512];   // 64 KB
    __shared__ float sp[8][64];       // cross-wave score reduce
    __shared__ float elds[64];        // exp(score - chunk max)
    __shared__ float sp2[4][512];     // ctx partial reduce

    const int tid  = threadIdx.x;
    const int wave = tid >> 6;
    const int lane = tid & 63;
    const int lm   = lane & 15;
    const int lq   = lane >> 4;
    const int blk  = blockIdx.x;
    const int b    = blk >> 5;              // 32 chunks per batch
    const size_t m0 = (size_t)blk * 64;     // global row base

    char* AhiB = (char*)Ahi;
    char* AloB = (char*)Alo;

    // ---- staging geometry: thread t -> row t>>3, 4 floats at k (t&7)*4
    const int srow = tid >> 3;
    const int skc8 = (tid & 7) * 8;                       // bf16 byte offset in row
    const unsigned srowB = (unsigned)srow * 1024;
    const unsigned swsr  = (unsigned)(srow & 7) << 4;
    const float* aptr = enc + m0 * DD + (size_t)srow * DD + (tid & 7) * 4;

    // ---- compute geometry
    const unsigned lq16 = (unsigned)lq * 16;
    const unsigned swlm = (unsigned)(lm & 7) << 4;
    unsigned arow[4];
    #pragma unroll
    for (int mf = 0; mf < 4; ++mf) arow[mf] = (unsigned)(mf * 16 + lm) * 1024;
    const short* Bw = Bt + (size_t)(wave * 64 + lm) * DD + lq * 8;

    f32x4 acc[4][4];
    #pragma unroll
    for (int i = 0; i < 4; ++i)
        #pragma unroll
        for (int j = 0; j < 4; ++j)
            acc[i][j] = (f32x4){0.f, 0.f, 0.f, 0.f};

    // ---- prologue: load slabs 0,1; write slab 0
    f32x4 stg[2];
    stg[0] = *(const f32x4*)(aptr);
    stg[1] = *(const f32x4*)(aptr + 32);
    write_slab(AhiB, AloB, srowB + ((unsigned)skc8 ^ swsr), stg[0]);
    __syncthreads();

    #pragma unroll
    for (int kt = 0; kt < 16; ++kt) {
        // prefetch slab kt+2 into the register pair slab kt vacated
        if (kt < 14) stg[kt & 1] = *(const f32x4*)(aptr + (kt + 2) * 32);
        // A frags from swizzled LDS (bf16 hi)
        const unsigned kx = ((unsigned)(kt * 64) + lq16) ^ swlm;
        bf16x8 af[4];
        #pragma unroll
        for (int mf = 0; mf < 4; ++mf)
            af[mf] = *(const bf16x8*)(AhiB + (arow[mf] + kx));
        // B frags straight from L2, 16 MFMA
        #pragma unroll
        for (int nf = 0; nf < 4; ++nf) {
            bf16x8 bfr = *(const bf16x8*)(Bw + nf * 16 * DD + kt * 32);
            #pragma unroll
            for (int mf = 0; mf < 4; ++mf)
                acc[mf][nf] = __builtin_amdgcn_mfma_f32_16x16x32_bf16(af[mf], bfr, acc[mf][nf], 0, 0, 0);
        }
        // convert + write slab kt+1 (distinct LDS region -> no WAR with kt reads)
        if (kt < 15) {
            unsigned off = srowB + (((unsigned)((kt + 1) * 64 + skc8)) ^ swsr);
            write_slab(AhiB, AloB, off, stg[(kt + 1) & 1]);
        }
        __syncthreads();
    }

    // ---- epilogue 1: tanh + dot v over this wave's n-slice
    const float* pb = p + (size_t)b * DD;
    float rowsum[4][4];
    #pragma unroll
    for (int mf = 0; mf < 4; ++mf)
        #pragma unroll
        for (int r = 0; r < 4; ++r) rowsum[mf][r] = 0.f;

    #pragma unroll
    for (int nf = 0; nf < 4; ++nf) {
        int n = wave * 64 + nf * 16 + lm;
        float pv = pb[n];
        float vv = va[n];
        #pragma unroll
        for (int mf = 0; mf < 4; ++mf)
            #pragma unroll
            for (int r = 0; r < 4; ++r)
                rowsum[mf][r] += fast_tanh(pv + acc[mf][nf][r]) * vv;
    }
    #pragma unroll
    for (int mf = 0; mf < 4; ++mf)
        #pragma unroll
        for (int r = 0; r < 4; ++r) {
            float s = rowsum[mf][r];
            s += __shfl_xor(s, 1);
            s += __shfl_xor(s, 2);
            s += __shfl_xor(s, 4);
            s += __shfl_xor(s, 8);
            rowsum[mf][r] = s;
        }
    if (lm == 0) {
        #pragma unroll
        for (int mf = 0; mf < 4; ++mf)
            #pragma unroll
            for (int r = 0; r < 4; ++r)
                sp[wave][mf * 16 + lq * 4 + r] = rowsum[mf][r];
    }
    __syncthreads();

    // ---- epilogue 2: full scores for 64 rows, chunk-local softmax partials
    if (tid < 64) {
        float s = 0.f;
        #pragma unroll
        for (int w = 0; w < 8; ++w) s += sp[w][tid];
        score[m0 + tid] = s;
        float mx = s;
        #pragma unroll
        for (int off = 32; off > 0; off >>= 1) mx = fmaxf(mx, __shfl_xor(mx, off));
        float e = __expf(s - mx);
        float l = e;
        #pragma unroll
        for (int off = 32; off > 0; off >>= 1) l += __shfl_xor(l, off);
        elds[tid] = e;
        if (tid == 0) {
            ml[(size_t)blk * 2]     = mx;
            ml[(size_t)blk * 2 + 1] = l;
        }
    }
    __syncthreads();

    // ---- epilogue 3: partial context pctx[d] = sum_s e_s * (hi+lo)[s][d]
    {
        const int q = tid & 127;       // d-quad: d0 = q*4
        const int g = tid >> 7;        // s-group: s = g*16 .. g*16+15
        const unsigned dbyte = (unsigned)q * 8;
        float c0 = 0.f, c1 = 0.f, c2 = 0.f, c3 = 0.f;
        #pragma unroll
        for (int si = 0; si < 16; ++si) {
            int s = g * 16 + si;
            float ev = elds[s];
            unsigned off = (unsigned)s * 1024 + (dbyte ^ ((unsigned)(s & 7) << 4));
            uint2 hv = *(const uint2*)(AhiB + off);
            uint2 lv = *(const uint2*)(AloB + off);
            c0 += ev * (__uint_as_float(hv.x << 16) + __uint_as_float(lv.x << 16));
            c1 += ev * (__uint_as_float(hv.x & 0xffff0000u) + __uint_as_float(lv.x & 0xffff0000u));
            c2 += ev * (__uint_as_float(hv.y << 16) + __uint_as_float(lv.y << 16));
            c3 += ev * (__uint_as_float(hv.y & 0xffff0000u) + __uint_as_float(lv.y & 0xffff0000u));
        }
        *(f32x4*)(&sp2[g][q * 4]) = (f32x4){c0, c1, c2, c3};
    }
    __syncthreads();
    {
        float v = sp2[0][tid] + sp2[1][tid] + sp2[2][tid] + sp2[3][tid];
        pctx[(size_t)blk * 512 + tid] = v;
    }
}

// ---------------------------------------------------------------------------
// Cross-chunk softmax combine: exact global M, L; rescale pctx; write ctx
// and alignment. One block per batch.
__global__ void combine_k(const float* __restrict__ score, const float* __restrict__ ml,
                          const float* __restrict__ pctx, float* __restrict__ ctx,
                          float* __restrict__ align) {
    __shared__ float sc[32];
    __shared__ float MB, LB;
    const int b = blockIdx.x, tid = threadIdx.x;   // 256 threads
    if (tid < 32) sc[tid] = ml[(size_t)(b * 32 + tid) * 2];
    __syncthreads();
    if (tid == 0) {
        float M = sc[0];
        #pragma unroll
        for (int i = 1; i < 32; ++i) M = fmaxf(M, sc[i]);
        float L = 0.f;
        for (int i = 0; i < 32; ++i) {
            float w = __expf(sc[i] - M);
            L += w * ml[(size_t)(b * 32 + i) * 2 + 1];
            sc[i] = w;                  // only thread 0 touches sc here
        }
        MB = M;
        LB = L;
    }
    __syncthreads();
    const float M = MB, Linv = 1.0f / LB;
    float a0 = 0.f, a1 = 0.f;
    for (int i = 0; i < 32; ++i) {
        float w = sc[i];
        const float* pc = pctx + (size_t)(b * 32 + i) * 512;
        a0 += w * pc[tid];
        a1 += w * pc[tid + 256];
    }
    ctx[(size_t)b * DD + tid]       = a0 * Linv;
    ctx[(size_t)b * DD + tid + 256] = a1 * Linv;
    const float* sr = score + (size_t)b * SS;
    float* al = align + (size_t)b * SS;
    #pragma unroll
    for (int i = 0; i < 8; ++i) {
        int s = i * 256 + tid;
        al[s] = __expf(sr[s] - M) * Linv;
    }
}

// ---------------------------------------------------------------------------
extern "C" void kernel_launch(void* const* d_in, const int* in_sizes, int n_in,
                              void* d_out, int out_size, void* d_ws, size_t ws_size,
                              hipStream_t stream) {
    const float* dec = (const float*)d_in[0];  // [64,1,512]
    const float* enc = (const float*)d_in[1];  // [64,2048,512]
    const float* W   = (const float*)d_in[2];  // [1024,512]
    const float* bt  = (const float*)d_in[3];  // [512]
    const float* va  = (const float*)d_in[4];  // [512,1]

    float* out   = (float*)d_out;
    float* ctx   = out;                 // 32768 floats (output 0)
    float* align = out + BB * DD;       // 131072 floats (output 1)

    char*  ws    = (char*)d_ws;
    short* Bt    = (short*)ws;                    // 524288 B : bf16 W_enc^T [n][k]
    float* p     = (float*)(ws + 524288);         // 131072 B : dec @ W_dec + b_t
    float* score = (float*)(ws + 655360);         // 524288 B : raw scores
    float* ml    = (float*)(ws + 1179648);        //  16384 B : (max, sum) per chunk
    float* pctx  = (float*)(ws + 1196032);        // 4194304 B: partial contexts

    prep_w<<<64, 256, 0, stream>>>(W, Bt);
    prep_p<<<dim3(BB, 2), 256, 0, stream>>>(dec, W, bt, p);
    fused_k<<<BB * 32, 512, 0, stream>>>(enc, Bt, p, va, score, ml, pctx);
    combine_k<<<BB, 256, 0, stream>>>(score, ml, pctx, ctx, align);
}